// Round 1
// baseline (315.094 us; speedup 1.0000x reference)
//
#include <hip/hip_runtime.h>
#include <cstdint>

#define NO 8
#define NT 4
#define ND 256
#define NH1 64
#define NH2 32
#define BM 32
#define KC 32
#define BNEPS 1e-5f

// ---------------- sorting: bucket rows by treatment ----------------
// ws int layout: [0..3]=cnt, [4..7]=base, [8..11]=cursor, [16..16+B)=perm

__global__ void k_zero(int* __restrict__ ws) {
    if (threadIdx.x < 16) ws[threadIdx.x] = 0;
}

__global__ void k_hist(const int* __restrict__ trt, int* __restrict__ cnt, int B) {
    __shared__ int loc[NT];
    const int tid = threadIdx.x;
    if (tid < NT) loc[tid] = 0;
    __syncthreads();
    const int i = blockIdx.x * blockDim.x + tid;
    if (i < B) atomicAdd(&loc[trt[i] & 3], 1);
    __syncthreads();
    if (tid < NT) atomicAdd(&cnt[tid], loc[tid]);
}

__global__ void k_prefix(int* __restrict__ ws) {
    int b = 0;
#pragma unroll
    for (int t = 0; t < NT; ++t) { ws[4 + t] = b; ws[8 + t] = b; b += ws[t]; }
}

__global__ void k_scatter(const int* __restrict__ trt, int* __restrict__ ws,
                          int* __restrict__ perm, int B) {
    __shared__ int loc[NT], gb[NT];
    const int tid = threadIdx.x;
    if (tid < NT) loc[tid] = 0;
    __syncthreads();
    const int i = blockIdx.x * blockDim.x + tid;
    int tt = 0, pos = 0;
    if (i < B) { tt = trt[i] & 3; pos = atomicAdd(&loc[tt], 1); }
    __syncthreads();
    if (tid < NT) gb[tid] = atomicAdd(&ws[8 + tid], loc[tid]);
    __syncthreads();
    if (i < B) perm[gb[tt] + pos] = i;
}

// ---------------- fused 3-layer expert MLP ----------------
// block: 256 threads, one treatment t, 32 rows (gathered via perm).
// phase1: H1[32][512(o,h)] via LDS-staged X^T and W1 chunks, 8x8 reg tile/thread.
// phase2: H2[32][256(o,k)] from swizzled Hs in LDS + W2 from L2.
// phase3: out[row][o] via shfl reduce.

__global__ __launch_bounds__(256, 2) void k_main(
    const float* __restrict__ X, const int* __restrict__ ws, const int* __restrict__ perm,
    const float* __restrict__ W1, const float* __restrict__ pb1, const float* __restrict__ pg1,
    const float* __restrict__ pbe1, const float* __restrict__ pm1, const float* __restrict__ pv1,
    const float* __restrict__ W2, const float* __restrict__ pb2, const float* __restrict__ pg2,
    const float* __restrict__ pbe2, const float* __restrict__ pm2, const float* __restrict__ pv2,
    const float* __restrict__ W3, const float* __restrict__ pb3, float* __restrict__ out)
{
    const int t = blockIdx.y;
    const int n = ws[t];                  // cnt[t]
    const int m0 = blockIdx.x * BM;
    if (m0 >= n) return;
    const int baset = ws[4 + t];
    const int tid = threadIdx.x;

    __shared__ float smem[17536];         // max(Ws 16384 + XsT 1152, Hs 16384)
    __shared__ int rid[BM];
    float* const Ws  = smem;              // [KC][512]  Ws[d][o*64+h]
    float* const XsT = smem + 16384;      // [KC][36]   XsT[d][r]
    float* const Hs  = smem;              // [BM][512]  swizzled, reused in phase 2

    if (tid < BM) {
        const int p = m0 + tid;
        rid[tid] = (p < n) ? perm[baset + p] : -1;
    }

    const int tr1 = tid & 3;              // row group: rows tr1*8 .. tr1*8+7
    const int hq  = tid >> 2;             // h index 0..63; cols are (o=j, h=hq)

    // fold BN1 per (o=j, t, h=hq)
    float bb1[NO], sc1[NO], sh1[NO];
#pragma unroll
    for (int j = 0; j < NO; ++j) {
        const int idx = (j * NT + t) * NH1 + hq;
        const float sc = pg1[idx] * rsqrtf(pv1[idx] + BNEPS);
        sc1[j] = sc;
        sh1[j] = pbe1[idx] - pm1[idx] * sc;
        bb1[j] = pb1[idx];
    }

    float acc[8][8];
#pragma unroll
    for (int i = 0; i < 8; ++i)
#pragma unroll
        for (int j = 0; j < 8; ++j) acc[i][j] = 0.f;

    const int rS = tid >> 3;              // staging row 0..31
    const int dS = (tid & 7) * 4;         // staging d 0..28 step 4

    __syncthreads();                      // rid visible

    for (int kc = 0; kc < ND; kc += KC) {
        __syncthreads();                  // previous chunk's reads done
        // stage X^T chunk (coalesced float4 global read, transposed LDS write)
        {
            float4 xv = make_float4(0.f, 0.f, 0.f, 0.f);
            const int rr = rid[rS];
            if (rr >= 0) xv = *(const float4*)(X + (size_t)rr * ND + kc + dS);
            XsT[(dS + 0) * 36 + rS] = xv.x;
            XsT[(dS + 1) * 36 + rS] = xv.y;
            XsT[(dS + 2) * 36 + rS] = xv.z;
            XsT[(dS + 3) * 36 + rS] = xv.w;
        }
        // stage W1 chunk: Ws[d][o*64+h] = W1[o][t][kc+d][h]
#pragma unroll
        for (int u = 0; u < 16; ++u) {
            const int f  = tid + u * 256;     // float4 id, 0..4095
            const int d  = f >> 7;            // 0..31
            const int c4 = (f & 127) * 4;     // 0..508
            const int o  = c4 >> 6;
            const int h  = c4 & 63;
            const float4 wv = *(const float4*)(W1 + (((size_t)(o * NT + t) * ND + kc + d) * NH1 + h));
            *(float4*)(Ws + d * 512 + c4) = wv;
        }
        __syncthreads();
#pragma unroll 4
        for (int d = 0; d < KC; ++d) {
            float a[8];
            const float4 a0 = *(const float4*)(XsT + d * 36 + tr1 * 8);
            const float4 a1 = *(const float4*)(XsT + d * 36 + tr1 * 8 + 4);
            a[0] = a0.x; a[1] = a0.y; a[2] = a0.z; a[3] = a0.w;
            a[4] = a1.x; a[5] = a1.y; a[6] = a1.z; a[7] = a1.w;
            float b[8];
#pragma unroll
            for (int j = 0; j < 8; ++j) b[j] = Ws[d * 512 + j * 64 + hq];
#pragma unroll
            for (int i = 0; i < 8; ++i)
#pragma unroll
                for (int j = 0; j < 8; ++j)
                    acc[i][j] = fmaf(a[i], b[j], acc[i][j]);
        }
    }
    __syncthreads();                      // all Ws/XsT reads done before Hs overwrite

    // bias + ReLU + BN1, store swizzled: Hs[r][ (h*8+o) ^ (r&24) ]
#pragma unroll
    for (int i = 0; i < 8; ++i) {
        const int r = tr1 * 8 + i;
        float z[8];
#pragma unroll
        for (int j = 0; j < 8; ++j) {
            const float zz = fmaxf(acc[i][j] + bb1[j], 0.f);
            z[j] = fmaf(zz, sc1[j], sh1[j]);
        }
        const int pc = (hq * 8) ^ (tr1 * 8);
        *(float4*)(Hs + r * 512 + pc)     = make_float4(z[0], z[1], z[2], z[3]);
        *(float4*)(Hs + r * 512 + pc + 4) = make_float4(z[4], z[5], z[6], z[7]);
    }
    __syncthreads();

    // ---------------- phase 2: layer 2 ----------------
    const int tr2 = tid & 3;
    const int q   = tid >> 2;             // 0..63
    const int o2  = q >> 3;               // 0..7
    const int k0  = (q & 7) * 4;          // 0..28

    float acc2[8][4];
#pragma unroll
    for (int i = 0; i < 8; ++i)
#pragma unroll
        for (int jj = 0; jj < 4; ++jj) acc2[i][jj] = 0.f;

    const size_t w2base = (size_t)(o2 * NT + t) * NH1 * NH2 + k0;
#pragma unroll 4
    for (int h = 0; h < NH1; ++h) {
        const float4 wv = *(const float4*)(W2 + w2base + (size_t)h * NH2);
#pragma unroll
        for (int i = 0; i < 8; ++i) {
            const float av = Hs[(size_t)(tr2 * 8 + i) * 512 + ((h * 8 + o2) ^ (tr2 * 8))];
            acc2[i][0] = fmaf(av, wv.x, acc2[i][0]);
            acc2[i][1] = fmaf(av, wv.y, acc2[i][1]);
            acc2[i][2] = fmaf(av, wv.z, acc2[i][2]);
            acc2[i][3] = fmaf(av, wv.w, acc2[i][3]);
        }
    }

    // BN2 fold + layer 3 weights
    float bb2[4], sc2[4], sh2[4], w3v[4];
#pragma unroll
    for (int jj = 0; jj < 4; ++jj) {
        const int idx = (o2 * NT + t) * NH2 + k0 + jj;
        const float sc = pg2[idx] * rsqrtf(pv2[idx] + BNEPS);
        sc2[jj] = sc;
        sh2[jj] = pbe2[idx] - pm2[idx] * sc;
        bb2[jj] = pb2[idx];
        w3v[jj] = W3[idx];
    }
    const float b3v = pb3[o2 * NT + t];

#pragma unroll
    for (int i = 0; i < 8; ++i) {
        float p = 0.f;
#pragma unroll
        for (int jj = 0; jj < 4; ++jj) {
            const float zz = fmaxf(acc2[i][jj] + bb2[jj], 0.f);
            p = fmaf(fmaf(zz, sc2[jj], sh2[jj]), w3v[jj], p);
        }
        p += __shfl_xor(p, 4);
        p += __shfl_xor(p, 8);
        p += __shfl_xor(p, 16);
        if ((q & 7) == 0) {
            const int r = rid[tr2 * 8 + i];
            if (r >= 0) out[(size_t)r * NO + o2] = p + b3v;
        }
    }
}

extern "C" void kernel_launch(void* const* d_in, const int* in_sizes, int n_in,
                              void* d_out, int out_size, void* d_ws, size_t ws_size,
                              hipStream_t stream) {
    const float* X   = (const float*)d_in[0];
    const int* trt   = (const int*)d_in[1];
    const float* W1  = (const float*)d_in[2];
    const float* b1  = (const float*)d_in[3];
    const float* g1  = (const float*)d_in[4];
    const float* be1 = (const float*)d_in[5];
    const float* m1  = (const float*)d_in[6];
    const float* v1  = (const float*)d_in[7];
    const float* W2  = (const float*)d_in[8];
    const float* b2  = (const float*)d_in[9];
    const float* g2  = (const float*)d_in[10];
    const float* be2 = (const float*)d_in[11];
    const float* m2  = (const float*)d_in[12];
    const float* v2  = (const float*)d_in[13];
    const float* W3  = (const float*)d_in[14];
    const float* b3  = (const float*)d_in[15];
    float* out = (float*)d_out;

    const int B = in_sizes[1];
    int* wsi  = (int*)d_ws;
    int* perm = wsi + 16;

    const int nb = (B + 255) / 256;
    k_zero<<<1, 64, 0, stream>>>(wsi);
    k_hist<<<nb, 256, 0, stream>>>(trt, wsi, B);
    k_prefix<<<1, 1, 0, stream>>>(wsi);
    k_scatter<<<nb, 256, 0, stream>>>(trt, wsi, perm, B);

    const int mt = (B + BM - 1) / BM;
    dim3 grid(mt, NT, 1);
    k_main<<<grid, 256, 0, stream>>>(X, wsi, perm, W1, b1, g1, be1, m1, v1,
                                     W2, b2, g2, be2, m2, v2, W3, b3, out);
}

// Round 2
// 75.203 us; speedup vs baseline: 4.1899x; 4.1899x over previous
//
#include <hip/hip_runtime.h>

typedef short bf16x8 __attribute__((ext_vector_type(8)));
typedef float f32x4 __attribute__((ext_vector_type(4)));

#define NO 8
#define NT 4
#define ND 256
#define NH1 64
#define NH2 32
#define BM 64
#define BNEPS 1e-5f

__device__ __forceinline__ unsigned bfpack2(float a, float b) {
    unsigned ua = __float_as_uint(a), ub = __float_as_uint(b);
    ua = (ua + 0x7FFFu + ((ua >> 16) & 1u)) >> 16;
    ub = (ub + 0x7FFFu + ((ub >> 16) & 1u)) >> 16;
    return ua | (ub << 16);
}

// ---------------- sorting: bucket rows by treatment ----------------
// ws layout: int[0..3]=cnt, [4..7]=base, [8..11]=cursor, [16..16+B)=perm,
// then W1T (bf16, 1 MB), W2T (bf16, 128 KB), all 16B-aligned.

__global__ void k_zero(int* __restrict__ ws) {
    if (threadIdx.x < 16) ws[threadIdx.x] = 0;
}

__global__ void k_hist(const int* __restrict__ trt, int* __restrict__ cnt, int B) {
    __shared__ int loc[NT];
    const int tid = threadIdx.x;
    if (tid < NT) loc[tid] = 0;
    __syncthreads();
    const int i = blockIdx.x * blockDim.x + tid;
    if (i < B) atomicAdd(&loc[trt[i] & 3], 1);
    __syncthreads();
    if (tid < NT) atomicAdd(&cnt[tid], loc[tid]);
}

__global__ void k_prefix(int* __restrict__ ws) {
    int b = 0;
#pragma unroll
    for (int t = 0; t < NT; ++t) { ws[4 + t] = b; ws[8 + t] = b; b += ws[t]; }
}

__global__ void k_scatter(const int* __restrict__ trt, int* __restrict__ ws,
                          int* __restrict__ perm, int B) {
    __shared__ int loc[NT], gb[NT];
    const int tid = threadIdx.x;
    if (tid < NT) loc[tid] = 0;
    __syncthreads();
    const int i = blockIdx.x * blockDim.x + tid;
    int tt = 0, pos = 0;
    if (i < B) { tt = trt[i] & 3; pos = atomicAdd(&loc[tt], 1); }
    __syncthreads();
    if (tid < NT) gb[tid] = atomicAdd(&ws[8 + tid], loc[tid]);
    __syncthreads();
    if (i < B) perm[gb[tt] + pos] = i;
}

// ---------------- weight prep: fp32 -> bf16 fragment-linear ----------------
// W1T layout: [t][c(4)][nt(32)][ks2(2)][kg(4)][n16(16)][j(8)]
//   n = nt*16+n16 (o=n>>6,h=n&63), d = c*64+ks2*32+kg*8+j
__global__ __launch_bounds__(256) void k_prep_w1(const float* __restrict__ W1,
                                                 unsigned* __restrict__ W1T4) {
    const int gi = blockIdx.x * 256 + threadIdx.x;           // 65536 total
    const int n16 = gi & 15, kg = (gi >> 4) & 3, ks2 = (gi >> 6) & 1,
              nt = (gi >> 7) & 31, c = (gi >> 12) & 3, t = gi >> 14;
    const int n = nt * 16 + n16, o = n >> 6, h = n & 63;
    const int db = c * 64 + ks2 * 32 + kg * 8;
    const float* src = W1 + ((size_t)(o * NT + t) * ND + db) * NH1 + h;
    float v[8];
#pragma unroll
    for (int j = 0; j < 8; ++j) v[j] = src[(size_t)j * NH1];
    uint4 q;
    q.x = bfpack2(v[0], v[1]); q.y = bfpack2(v[2], v[3]);
    q.z = bfpack2(v[4], v[5]); q.w = bfpack2(v[6], v[7]);
    ((uint4*)W1T4)[gi] = q;
}

// W2T layout: [t][o][kt(2)][ks(2)][kg(4)][m16(16)][j(8)]
//   k2 = kt*16+m16, h = ks*32+kg*8+j
__global__ __launch_bounds__(256) void k_prep_w2(const float* __restrict__ W2,
                                                 unsigned* __restrict__ W2T4) {
    const int gi = blockIdx.x * 256 + threadIdx.x;           // 8192 total
    const int m16 = gi & 15, kg = (gi >> 4) & 3, ks = (gi >> 6) & 1,
              kt = (gi >> 7) & 1, o = (gi >> 8) & 7, t = gi >> 11;
    const int k2 = kt * 16 + m16, hb = ks * 32 + kg * 8;
    const float* src = W2 + ((size_t)(o * NT + t) * NH1 + hb) * NH2 + k2;
    float v[8];
#pragma unroll
    for (int j = 0; j < 8; ++j) v[j] = src[(size_t)j * NH2];
    uint4 q;
    q.x = bfpack2(v[0], v[1]); q.y = bfpack2(v[2], v[3]);
    q.z = bfpack2(v[4], v[5]); q.w = bfpack2(v[6], v[7]);
    ((uint4*)W2T4)[gi] = q;
}

// ---------------- fused 3-layer expert MLP (MFMA) ----------------
// Computes H^T = W1T x X^T so C-frag rows = feature dim (4 consecutive per lane).
__global__ __launch_bounds__(256, 2) void k_main(
    const float* __restrict__ X, const int* __restrict__ ws, const int* __restrict__ perm,
    const unsigned short* __restrict__ W1T, const unsigned short* __restrict__ W2T,
    const float* __restrict__ pb1, const float* __restrict__ pg1, const float* __restrict__ pbe1,
    const float* __restrict__ pm1, const float* __restrict__ pv1,
    const float* __restrict__ pb2, const float* __restrict__ pg2, const float* __restrict__ pbe2,
    const float* __restrict__ pm2, const float* __restrict__ pv2,
    const float* __restrict__ W3, const float* __restrict__ pb3, float* __restrict__ out)
{
    const int t = blockIdx.y;
    const int n_t = ws[t];
    const int m0 = blockIdx.x * BM;
    if (m0 >= n_t) return;
    const int base = ws[4 + t];
    const int tid = threadIdx.x;
    const int w = tid >> 6;
    const int l = tid & 63;

    __shared__ char BL[65536];     // W1T chunk; later aliased as Hr[64 r][512 n] bf16 (swizzled)
    __shared__ char XL[8192];      // X^T tile [64 r][64 d] bf16 (swizzled)
    __shared__ int rid[BM];

    if (tid < BM) {
        const int p = m0 + tid;
        rid[tid] = (p < n_t) ? perm[base + p] : -1;
    }
    __syncthreads();

    const int rloc = tid >> 2;
    const int rr = rid[rloc];
    const int k0 = (tid & 3) * 16;
    const unsigned swX = (unsigned)((rloc & 7) << 4);

    f32x4 acc[8][4];
#pragma unroll
    for (int nt = 0; nt < 8; ++nt)
#pragma unroll
        for (int rt = 0; rt < 4; ++rt) acc[nt][rt] = (f32x4){0.f, 0.f, 0.f, 0.f};

    const char* W1Tt = (const char*)W1T + (size_t)t * 262144;
    const int ln4 = (l >> 4) * 4;

    for (int c = 0; c < 4; ++c) {
        __syncthreads();
        // --- stage X chunk: gather fp32, cvt bf16, swizzled LDS write ---
        float4 x0 = {0,0,0,0}, x1 = {0,0,0,0}, x2 = {0,0,0,0}, x3 = {0,0,0,0};
        if (rr >= 0) {
            const float* xp = X + (size_t)rr * ND + c * 64 + k0;
            x0 = *(const float4*)(xp);
            x1 = *(const float4*)(xp + 4);
            x2 = *(const float4*)(xp + 8);
            x3 = *(const float4*)(xp + 12);
        }
        uint4 q0, q1;
        q0.x = bfpack2(x0.x, x0.y); q0.y = bfpack2(x0.z, x0.w);
        q0.z = bfpack2(x1.x, x1.y); q0.w = bfpack2(x1.z, x1.w);
        q1.x = bfpack2(x2.x, x2.y); q1.y = bfpack2(x2.z, x2.w);
        q1.z = bfpack2(x3.x, x3.y); q1.w = bfpack2(x3.z, x3.w);
        *(uint4*)(XL + rloc * 128 + (((unsigned)(k0 * 2)) ^ swX)) = q0;
        *(uint4*)(XL + rloc * 128 + (((unsigned)(k0 * 2 + 16)) ^ swX)) = q1;
        // --- stage W1T chunk (64 KB) via global_load_lds width=16, linear ---
        const char* src = W1Tt + c * 65536;
#pragma unroll
        for (int u = 0; u < 16; ++u) {
            const int sl = (u * 4 + w) * 1024 + l * 16;
            __builtin_amdgcn_global_load_lds(
                (const __attribute__((address_space(1))) void*)(src + sl),
                (__attribute__((address_space(3))) void*)(BL + sl), 16, 0, 0);
        }
        __syncthreads();
        // --- compute: 64 MFMAs/wave per chunk ---
#pragma unroll
        for (int ks2 = 0; ks2 < 2; ++ks2) {
            bf16x8 aA[8];
#pragma unroll
            for (int nt = 0; nt < 8; ++nt)
                aA[nt] = *(const bf16x8*)(BL + ((w * 8 + nt) * 128 + ks2 * 64 + l) * 16);
#pragma unroll
            for (int rt = 0; rt < 4; ++rt) {
                const int r = rt * 16 + (l & 15);
                const unsigned dby = (unsigned)((ks2 * 32 + (l >> 4) * 8) * 2) ^ (unsigned)((r & 7) << 4);
                const bf16x8 bX = *(const bf16x8*)(XL + r * 128 + dby);
#pragma unroll
                for (int nt = 0; nt < 8; ++nt)
                    acc[nt][rt] = __builtin_amdgcn_mfma_f32_16x16x32_bf16(aA[nt], bX, acc[nt][rt], 0, 0, 0);
            }
        }
    }
    __syncthreads();   // all W1T reads done; BL becomes Hr

    // --- epilogue L1: bias+ReLU+BN1, bf16, swizzled row-major Hr[r][n] ---
#pragma unroll
    for (int nt = 0; nt < 8; ++nt) {
        const int n0 = (w * 8 + nt) * 16 + ln4;
        const int o = n0 >> 6, h0 = n0 & 63;
        const int pidx = (o * NT + t) * NH1 + h0;
        const float4 b1v = *(const float4*)(pb1 + pidx);
        const float4 g1v = *(const float4*)(pg1 + pidx);
        const float4 be1v = *(const float4*)(pbe1 + pidx);
        const float4 m1v = *(const float4*)(pm1 + pidx);
        const float4 v1v = *(const float4*)(pv1 + pidx);
        float bb[4], sc[4], sh[4];
        bb[0] = b1v.x; sc[0] = g1v.x * rsqrtf(v1v.x + BNEPS); sh[0] = be1v.x - m1v.x * sc[0];
        bb[1] = b1v.y; sc[1] = g1v.y * rsqrtf(v1v.y + BNEPS); sh[1] = be1v.y - m1v.y * sc[1];
        bb[2] = b1v.z; sc[2] = g1v.z * rsqrtf(v1v.z + BNEPS); sh[2] = be1v.z - m1v.z * sc[2];
        bb[3] = b1v.w; sc[3] = g1v.w * rsqrtf(v1v.w + BNEPS); sh[3] = be1v.w - m1v.w * sc[3];
#pragma unroll
        for (int rt = 0; rt < 4; ++rt) {
            const int r = rt * 16 + (l & 15);
            const f32x4 a = acc[nt][rt];
            const float z0 = fmaf(fmaxf(a[0] + bb[0], 0.f), sc[0], sh[0]);
            const float z1 = fmaf(fmaxf(a[1] + bb[1], 0.f), sc[1], sh[1]);
            const float z2 = fmaf(fmaxf(a[2] + bb[2], 0.f), sc[2], sh[2]);
            const float z3 = fmaf(fmaxf(a[3] + bb[3], 0.f), sc[3], sh[3]);
            uint2 pk;
            pk.x = bfpack2(z0, z1); pk.y = bfpack2(z2, z3);
            *(uint2*)(BL + r * 1024 + (((unsigned)(n0 * 2)) ^ (unsigned)((r & 7) << 4))) = pk;
        }
    }
    // wave reads only its own Hr columns -> no barrier needed

    // --- layer 2: C2T[k2][r] = W2T x H, MFMA ---
    bf16x8 aW[2][2][2];   // [oo][kt][ks]
#pragma unroll
    for (int oo = 0; oo < 2; ++oo) {
        const int o = w * 2 + oo;
#pragma unroll
        for (int kt = 0; kt < 2; ++kt)
#pragma unroll
            for (int ks = 0; ks < 2; ++ks)
                aW[oo][kt][ks] = *(const bf16x8*)((const char*)W2T +
                    ((((size_t)t * NO + o) * 2 + kt) * 2 + ks) * 1024 + l * 16);
    }
    f32x4 acc2[2][2][4];
#pragma unroll
    for (int oo = 0; oo < 2; ++oo)
#pragma unroll
        for (int kt = 0; kt < 2; ++kt)
#pragma unroll
            for (int rt2 = 0; rt2 < 4; ++rt2) acc2[oo][kt][rt2] = (f32x4){0.f, 0.f, 0.f, 0.f};

#pragma unroll
    for (int rt2 = 0; rt2 < 4; ++rt2) {
        const int r = rt2 * 16 + (l & 15);
        const unsigned swz = (unsigned)((r & 7) << 4);
#pragma unroll
        for (int ks = 0; ks < 2; ++ks) {
            const int nb = ks * 32 + (l >> 4) * 8;
#pragma unroll
            for (int oo = 0; oo < 2; ++oo) {
                const int n8 = (w * 2 + oo) * 64 + nb;
                const bf16x8 bH = *(const bf16x8*)(BL + r * 1024 + (((unsigned)(n8 * 2)) ^ swz));
#pragma unroll
                for (int kt = 0; kt < 2; ++kt)
                    acc2[oo][kt][rt2] = __builtin_amdgcn_mfma_f32_16x16x32_bf16(aW[oo][kt][ks], bH, acc2[oo][kt][rt2], 0, 0, 0);
            }
        }
    }

    // --- BN2 + ReLU + layer3 dot, reduce over k2 lane groups ---
    float p[2][4];
#pragma unroll
    for (int oo = 0; oo < 2; ++oo)
#pragma unroll
        for (int rt2 = 0; rt2 < 4; ++rt2) p[oo][rt2] = 0.f;

#pragma unroll
    for (int oo = 0; oo < 2; ++oo) {
        const int o = w * 2 + oo;
#pragma unroll
        for (int kt = 0; kt < 2; ++kt) {
            const int k2 = kt * 16 + ln4;
            const int pidx = (o * NT + t) * NH2 + k2;
            const float4 b2v = *(const float4*)(pb2 + pidx);
            const float4 g2v = *(const float4*)(pg2 + pidx);
            const float4 be2v = *(const float4*)(pbe2 + pidx);
            const float4 m2v = *(const float4*)(pm2 + pidx);
            const float4 v2v = *(const float4*)(pv2 + pidx);
            const float4 w3v = *(const float4*)(W3 + pidx);
            float bb[4], A3[4], C3[4];
            {
                const float s0 = g2v.x * rsqrtf(v2v.x + BNEPS);
                const float s1 = g2v.y * rsqrtf(v2v.y + BNEPS);
                const float s2 = g2v.z * rsqrtf(v2v.z + BNEPS);
                const float s3 = g2v.w * rsqrtf(v2v.w + BNEPS);
                bb[0] = b2v.x; A3[0] = s0 * w3v.x; C3[0] = (be2v.x - m2v.x * s0) * w3v.x;
                bb[1] = b2v.y; A3[1] = s1 * w3v.y; C3[1] = (be2v.y - m2v.y * s1) * w3v.y;
                bb[2] = b2v.z; A3[2] = s2 * w3v.z; C3[2] = (be2v.z - m2v.z * s2) * w3v.z;
                bb[3] = b2v.w; A3[3] = s3 * w3v.w; C3[3] = (be2v.w - m2v.w * s3) * w3v.w;
            }
#pragma unroll
            for (int rt2 = 0; rt2 < 4; ++rt2) {
                const f32x4 a = acc2[oo][kt][rt2];
                float s = fmaf(fmaxf(a[0] + bb[0], 0.f), A3[0], C3[0]);
                s = fmaf(fmaxf(a[1] + bb[1], 0.f), A3[1], s + C3[1]);
                s = fmaf(fmaxf(a[2] + bb[2], 0.f), A3[2], s + C3[2]);
                s = fmaf(fmaxf(a[3] + bb[3], 0.f), A3[3], s + C3[3]);
                p[oo][rt2] += s;
            }
        }
    }
#pragma unroll
    for (int oo = 0; oo < 2; ++oo)
#pragma unroll
        for (int rt2 = 0; rt2 < 4; ++rt2) {
            float v = p[oo][rt2];
            v += __shfl_xor(v, 16);
            v += __shfl_xor(v, 32);
            p[oo][rt2] = v;
        }

    const int oo_s = l >> 5;
    const int bsel = (l >> 4) & 1;
    const int o_s = w * 2 + oo_s;
    const float b3v = pb3[o_s * NT + t];
    const float v0 = oo_s ? (bsel ? p[1][1] : p[1][0]) : (bsel ? p[0][1] : p[0][0]);
    const float v1 = oo_s ? (bsel ? p[1][3] : p[1][2]) : (bsel ? p[0][3] : p[0][2]);
    const int rg0 = bsel * 16 + (l & 15);
    const int ra = rid[rg0], rb = rid[rg0 + 32];
    if (ra >= 0) out[(size_t)ra * NO + o_s] = v0 + b3v;
    if (rb >= 0) out[(size_t)rb * NO + o_s] = v1 + b3v;
}

extern "C" void kernel_launch(void* const* d_in, const int* in_sizes, int n_in,
                              void* d_out, int out_size, void* d_ws, size_t ws_size,
                              hipStream_t stream) {
    const float* X   = (const float*)d_in[0];
    const int* trt   = (const int*)d_in[1];
    const float* W1  = (const float*)d_in[2];
    const float* b1  = (const float*)d_in[3];
    const float* g1  = (const float*)d_in[4];
    const float* be1 = (const float*)d_in[5];
    const float* m1  = (const float*)d_in[6];
    const float* v1  = (const float*)d_in[7];
    const float* W2  = (const float*)d_in[8];
    const float* b2  = (const float*)d_in[9];
    const float* g2  = (const float*)d_in[10];
    const float* be2 = (const float*)d_in[11];
    const float* m2  = (const float*)d_in[12];
    const float* v2  = (const float*)d_in[13];
    const float* W3  = (const float*)d_in[14];
    const float* b3  = (const float*)d_in[15];
    float* out = (float*)d_out;

    const int B = in_sizes[1];
    int* wsi  = (int*)d_ws;
    int* perm = wsi + 16;
    char* wsb = (char*)d_ws;
    unsigned* W1T4 = (unsigned*)(wsb + 64 + (size_t)B * 4);            // 16B aligned
    unsigned* W2T4 = (unsigned*)(wsb + 64 + (size_t)B * 4 + 1048576);

    const int nb = (B + 255) / 256;
    k_zero<<<1, 64, 0, stream>>>(wsi);
    k_hist<<<nb, 256, 0, stream>>>(trt, wsi, B);
    k_prefix<<<1, 1, 0, stream>>>(wsi);
    k_scatter<<<nb, 256, 0, stream>>>(trt, wsi, perm, B);
    k_prep_w1<<<256, 256, 0, stream>>>(W1, W1T4);
    k_prep_w2<<<32, 256, 0, stream>>>(W2, W2T4);

    const int mt = (B + BM - 1) / BM;
    dim3 grid(mt, NT, 1);
    k_main<<<grid, 256, 0, stream>>>(X, wsi, perm,
                                     (const unsigned short*)W1T4, (const unsigned short*)W2T4,
                                     b1, g1, be1, m1, v1, b2, g2, be2, m2, v2, W3, b3, out);
}

// Round 4
// 67.999 us; speedup vs baseline: 4.6338x; 1.1059x over previous
//
#include <hip/hip_runtime.h>
#include <cstdint>

typedef short bf16x8 __attribute__((ext_vector_type(8)));
typedef float f32x4 __attribute__((ext_vector_type(4)));

#define NO 8
#define NT 4
#define ND 256
#define NH1 64
#define NH2 32
#define BM 64
#define BNEPS 1e-5f

__device__ __forceinline__ unsigned bfpack2(float a, float b) {
    unsigned ua = __float_as_uint(a), ub = __float_as_uint(b);
    ua = (ua + 0x7FFFu + ((ua >> 16) & 1u)) >> 16;
    ub = (ub + 0x7FFFu + ((ub >> 16) & 1u)) >> 16;
    return ua | (ub << 16);
}

// ws layout: int[0..3]=cnt, [4..7]=padded base, [8]=padded total, [12..15]=cursor,
// [16..16+B+256)=perm (filled -1; pad slots stay -1), then W1T (1MB), W2T (128KB).

__global__ void k_init(int* __restrict__ ws, int* __restrict__ perm, int n) {
    const int gi = blockIdx.x * blockDim.x + threadIdx.x;
    if (gi < 16) ws[gi] = 0;
    if (gi < n) perm[gi] = -1;
}

__global__ void k_hist(const int* __restrict__ trt, int* __restrict__ cnt, int B) {
    __shared__ int loc[NT];
    const int tid = threadIdx.x;
    if (tid < NT) loc[tid] = 0;
    __syncthreads();
    const int i = blockIdx.x * blockDim.x + tid;
    if (i < B) atomicAdd(&loc[trt[i] & 3], 1);
    __syncthreads();
    if (tid < NT) atomicAdd(&cnt[tid], loc[tid]);
}

__global__ void k_prefix(int* __restrict__ ws) {
    int b = 0;
#pragma unroll
    for (int t = 0; t < NT; ++t) {
        ws[4 + t] = b; ws[12 + t] = b;
        b += (ws[t] + BM - 1) & ~(BM - 1);       // 64-aligned buckets
    }
    ws[8] = b;
}

__global__ void k_scatter(const int* __restrict__ trt, int* __restrict__ ws,
                          int* __restrict__ perm, int B) {
    __shared__ int loc[NT], gb[NT];
    const int tid = threadIdx.x;
    if (tid < NT) loc[tid] = 0;
    __syncthreads();
    const int i = blockIdx.x * blockDim.x + tid;
    int tt = 0, pos = 0;
    if (i < B) { tt = trt[i] & 3; pos = atomicAdd(&loc[tt], 1); }
    __syncthreads();
    if (tid < NT) gb[tid] = atomicAdd(&ws[12 + tid], loc[tid]);
    __syncthreads();
    if (i < B) perm[gb[tt] + pos] = i;
}

// ---------------- fused weight prep: fp32 -> bf16 fragment-linear ----------------
// W1T: frag gi = ((t*8 + c)*32 + nt)*64 + lane; lane = kg*16 + n16;
//      n = nt*16+n16 (o=n>>6,h=n&63), k = c*32 + kg*8 + j  (KC=32 chunks, contiguous)
// W2T: [t][o][kt(2)][ks(2)][kg(4)][m16(16)][j(8)]
__global__ __launch_bounds__(256) void k_prep(const float* __restrict__ W1,
                                              const float* __restrict__ W2,
                                              unsigned* __restrict__ W1T4,
                                              unsigned* __restrict__ W2T4) {
    const int bid = blockIdx.x, tid = threadIdx.x;
    if (bid < 256) {
        const int gi = bid * 256 + tid;                   // 65536 frags
        const int lane = gi & 63, nt = (gi >> 6) & 31, c = (gi >> 11) & 7, t = gi >> 14;
        const int n16 = lane & 15, kg = lane >> 4;
        const int n = nt * 16 + n16, o = n >> 6, h = n & 63;
        const int k0 = c * 32 + kg * 8;
        const float* src = W1 + ((size_t)(o * NT + t) * ND + k0) * NH1 + h;
        float v[8];
#pragma unroll
        for (int j = 0; j < 8; ++j) v[j] = src[(size_t)j * NH1];
        uint4 q;
        q.x = bfpack2(v[0], v[1]); q.y = bfpack2(v[2], v[3]);
        q.z = bfpack2(v[4], v[5]); q.w = bfpack2(v[6], v[7]);
        ((uint4*)W1T4)[gi] = q;
    } else {
        const int gi = (bid - 256) * 256 + tid;           // 8192 frags
        const int m16 = gi & 15, kg = (gi >> 4) & 3, ks = (gi >> 6) & 1,
                  kt = (gi >> 7) & 1, o = (gi >> 8) & 7, t = gi >> 11;
        const int k2 = kt * 16 + m16, hb = ks * 32 + kg * 8;
        const float* src = W2 + ((size_t)(o * NT + t) * NH1 + hb) * NH2 + k2;
        float v[8];
#pragma unroll
        for (int j = 0; j < 8; ++j) v[j] = src[(size_t)j * NH2];
        uint4 q;
        q.x = bfpack2(v[0], v[1]); q.y = bfpack2(v[2], v[3]);
        q.z = bfpack2(v[4], v[5]); q.w = bfpack2(v[6], v[7]);
        ((uint4*)W2T4)[gi] = q;
    }
}

// ---------------- fused 3-layer expert MLP, double-buffered pipeline ----------------
__global__ __launch_bounds__(256, 2) void k_main(
    const float* __restrict__ X, const int* __restrict__ ws, const int* __restrict__ perm,
    const unsigned short* __restrict__ W1T, const unsigned short* __restrict__ W2T,
    const float* __restrict__ pb1, const float* __restrict__ pg1, const float* __restrict__ pbe1,
    const float* __restrict__ pm1, const float* __restrict__ pv1,
    const float* __restrict__ pb2, const float* __restrict__ pg2, const float* __restrict__ pbe2,
    const float* __restrict__ pm2, const float* __restrict__ pv2,
    const float* __restrict__ W3, const float* __restrict__ pb3, float* __restrict__ out)
{
    const int m0 = blockIdx.x * BM;
    if (m0 >= ws[8]) return;
    const int t = (m0 >= ws[5]) + (m0 >= ws[6]) + (m0 >= ws[7]);
    const int tid = threadIdx.x;
    const int w = tid >> 6;
    const int l = tid & 63;

    // [0,65536): W dbuf (2x32768), aliased as Hr[64][512] bf16 swizzled in epilogue
    // [65536, 75776): X dbuf (2 x 64rows x 80B)
    __shared__ __align__(16) char LDS[75776];

    const int rid_reg = perm[m0 + l];          // every wave holds all 64 row ids
    const int xrow = tid >> 2;                 // X-stage row 0..63
    const int rr = __shfl(rid_reg, xrow);
    const int xdo = (tid & 3) * 8;             // d-offset (floats) within chunk

    f32x4 acc[8][4];
#pragma unroll
    for (int nt = 0; nt < 8; ++nt)
#pragma unroll
        for (int rt = 0; rt < 4; ++rt) acc[nt][rt] = (f32x4){0.f, 0.f, 0.f, 0.f};

    const char* W1Tt = (const char*)W1T + (size_t)t * 262144;
    const int ln4 = (l >> 4) * 4;

    // ---- prologue: stage chunk 0 into buf 0 ----
    {
#pragma unroll
        for (int u = 0; u < 8; ++u) {
            const int sl = (u * 4 + w) * 1024 + l * 16;
            __builtin_amdgcn_global_load_lds(
                (const __attribute__((address_space(1))) void*)(W1Tt + sl),
                (__attribute__((address_space(3))) void*)(LDS + sl), 16, 0, 0);
        }
        float4 xa = {0,0,0,0}, xb = {0,0,0,0};
        if (rr >= 0) {
            const float* xp = X + (size_t)rr * ND + xdo;
            xa = *(const float4*)xp; xb = *(const float4*)(xp + 4);
        }
        uint4 q;
        q.x = bfpack2(xa.x, xa.y); q.y = bfpack2(xa.z, xa.w);
        q.z = bfpack2(xb.x, xb.y); q.w = bfpack2(xb.z, xb.w);
        *(uint4*)(LDS + 65536 + xrow * 80 + (tid & 3) * 16) = q;
    }
    __syncthreads();

    // ---- main loop: stage(c+1) -> compute(c) -> write X(c+1) -> barrier ----
    int cur = 0;
    for (int c = 0; c < 8; ++c) {
        const int nxt = cur ^ 1;
        float4 xa = {0,0,0,0}, xb = {0,0,0,0};
        if (c < 7) {
            const char* src = W1Tt + (c + 1) * 32768;
#pragma unroll
            for (int u = 0; u < 8; ++u) {
                const int sl = (u * 4 + w) * 1024 + l * 16;
                __builtin_amdgcn_global_load_lds(
                    (const __attribute__((address_space(1))) void*)(src + sl),
                    (__attribute__((address_space(3))) void*)(LDS + nxt * 32768 + sl), 16, 0, 0);
            }
            if (rr >= 0) {
                const float* xp = X + (size_t)rr * ND + (c + 1) * 32 + xdo;
                xa = *(const float4*)xp; xb = *(const float4*)(xp + 4);
            }
        }
        // compute chunk c
        bf16x8 aA[8];
#pragma unroll
        for (int nt = 0; nt < 8; ++nt)
            aA[nt] = *(const bf16x8*)(LDS + cur * 32768 + (w * 8 + nt) * 1024 + l * 16);
#pragma unroll
        for (int rt = 0; rt < 4; ++rt) {
            const bf16x8 bX = *(const bf16x8*)(LDS + 65536 + cur * 5120 +
                                               (rt * 16 + (l & 15)) * 80 + (l >> 4) * 16);
#pragma unroll
            for (int nt = 0; nt < 8; ++nt)
                acc[nt][rt] = __builtin_amdgcn_mfma_f32_16x16x32_bf16(aA[nt], bX, acc[nt][rt], 0, 0, 0);
        }
        if (c < 7) {
            uint4 q;
            q.x = bfpack2(xa.x, xa.y); q.y = bfpack2(xa.z, xa.w);
            q.z = bfpack2(xb.x, xb.y); q.w = bfpack2(xb.z, xb.w);
            *(uint4*)(LDS + 65536 + nxt * 5120 + xrow * 80 + (tid & 3) * 16) = q;
        }
        __syncthreads();
        cur = nxt;
    }

    // --- epilogue L1: bias+ReLU+BN1, bf16, swizzled row-major Hr[r][n] over W region ---
#pragma unroll
    for (int nt = 0; nt < 8; ++nt) {
        const int n0 = (w * 8 + nt) * 16 + ln4;
        const int o = n0 >> 6, h0 = n0 & 63;
        const int pidx = (o * NT + t) * NH1 + h0;
        const float4 b1v = *(const float4*)(pb1 + pidx);
        const float4 g1v = *(const float4*)(pg1 + pidx);
        const float4 be1v = *(const float4*)(pbe1 + pidx);
        const float4 m1v = *(const float4*)(pm1 + pidx);
        const float4 v1v = *(const float4*)(pv1 + pidx);
        float bb[4], sc[4], sh[4];
        bb[0] = b1v.x; sc[0] = g1v.x * rsqrtf(v1v.x + BNEPS); sh[0] = be1v.x - m1v.x * sc[0];
        bb[1] = b1v.y; sc[1] = g1v.y * rsqrtf(v1v.y + BNEPS); sh[1] = be1v.y - m1v.y * sc[1];
        bb[2] = b1v.z; sc[2] = g1v.z * rsqrtf(v1v.z + BNEPS); sh[2] = be1v.z - m1v.z * sc[2];
        bb[3] = b1v.w; sc[3] = g1v.w * rsqrtf(v1v.w + BNEPS); sh[3] = be1v.w - m1v.w * sc[3];
#pragma unroll
        for (int rt = 0; rt < 4; ++rt) {
            const int r = rt * 16 + (l & 15);
            const f32x4 a = acc[nt][rt];
            const float z0 = fmaf(fmaxf(a[0] + bb[0], 0.f), sc[0], sh[0]);
            const float z1 = fmaf(fmaxf(a[1] + bb[1], 0.f), sc[1], sh[1]);
            const float z2 = fmaf(fmaxf(a[2] + bb[2], 0.f), sc[2], sh[2]);
            const float z3 = fmaf(fmaxf(a[3] + bb[3], 0.f), sc[3], sh[3]);
            uint2 pk;
            pk.x = bfpack2(z0, z1); pk.y = bfpack2(z2, z3);
            *(uint2*)(LDS + r * 1024 + (((unsigned)(n0 * 2)) ^ (unsigned)((r & 7) << 4))) = pk;
        }
    }
    // each wave reads only its own Hr columns -> no barrier needed

    // --- layer 2: C2T[k2][r] = W2T x H, MFMA ---
    bf16x8 aW[2][2][2];   // [oo][kt][ks]
#pragma unroll
    for (int oo = 0; oo < 2; ++oo) {
        const int o = w * 2 + oo;
#pragma unroll
        for (int kt = 0; kt < 2; ++kt)
#pragma unroll
            for (int ks = 0; ks < 2; ++ks)
                aW[oo][kt][ks] = *(const bf16x8*)((const char*)W2T +
                    ((((size_t)t * NO + o) * 2 + kt) * 2 + ks) * 1024 + l * 16);
    }
    f32x4 acc2[2][2][4];
#pragma unroll
    for (int oo = 0; oo < 2; ++oo)
#pragma unroll
        for (int kt = 0; kt < 2; ++kt)
#pragma unroll
            for (int rt2 = 0; rt2 < 4; ++rt2) acc2[oo][kt][rt2] = (f32x4){0.f, 0.f, 0.f, 0.f};

#pragma unroll
    for (int rt2 = 0; rt2 < 4; ++rt2) {
        const int r = rt2 * 16 + (l & 15);
        const unsigned swz = (unsigned)((r & 7) << 4);
#pragma unroll
        for (int ks = 0; ks < 2; ++ks) {
            const int nb = ks * 32 + (l >> 4) * 8;
#pragma unroll
            for (int oo = 0; oo < 2; ++oo) {
                const int n8 = (w * 2 + oo) * 64 + nb;
                const bf16x8 bH = *(const bf16x8*)(LDS + r * 1024 + (((unsigned)(n8 * 2)) ^ swz));
#pragma unroll
                for (int kt = 0; kt < 2; ++kt)
                    acc2[oo][kt][rt2] = __builtin_amdgcn_mfma_f32_16x16x32_bf16(aW[oo][kt][ks], bH, acc2[oo][kt][rt2], 0, 0, 0);
            }
        }
    }

    // --- BN2 + ReLU + layer3 dot, reduce over k2 lane groups ---
    float p[2][4];
#pragma unroll
    for (int oo = 0; oo < 2; ++oo)
#pragma unroll
        for (int rt2 = 0; rt2 < 4; ++rt2) p[oo][rt2] = 0.f;

#pragma unroll
    for (int oo = 0; oo < 2; ++oo) {
        const int o = w * 2 + oo;
#pragma unroll
        for (int kt = 0; kt < 2; ++kt) {
            const int k2 = kt * 16 + ln4;
            const int pidx = (o * NT + t) * NH2 + k2;
            const float4 b2v = *(const float4*)(pb2 + pidx);
            const float4 g2v = *(const float4*)(pg2 + pidx);
            const float4 be2v = *(const float4*)(pbe2 + pidx);
            const float4 m2v = *(const float4*)(pm2 + pidx);
            const float4 v2v = *(const float4*)(pv2 + pidx);
            const float4 w3v = *(const float4*)(W3 + pidx);
            float bb[4], A3[4], C3[4];
            {
                const float s0 = g2v.x * rsqrtf(v2v.x + BNEPS);
                const float s1 = g2v.y * rsqrtf(v2v.y + BNEPS);
                const float s2 = g2v.z * rsqrtf(v2v.z + BNEPS);
                const float s3 = g2v.w * rsqrtf(v2v.w + BNEPS);
                bb[0] = b2v.x; A3[0] = s0 * w3v.x; C3[0] = (be2v.x - m2v.x * s0) * w3v.x;
                bb[1] = b2v.y; A3[1] = s1 * w3v.y; C3[1] = (be2v.y - m2v.y * s1) * w3v.y;
                bb[2] = b2v.z; A3[2] = s2 * w3v.z; C3[2] = (be2v.z - m2v.z * s2) * w3v.z;
                bb[3] = b2v.w; A3[3] = s3 * w3v.w; C3[3] = (be2v.w - m2v.w * s3) * w3v.w;
            }
#pragma unroll
            for (int rt2 = 0; rt2 < 4; ++rt2) {
                const f32x4 a = acc2[oo][kt][rt2];
                float s = fmaf(fmaxf(a[0] + bb[0], 0.f), A3[0], C3[0]);
                s = fmaf(fmaxf(a[1] + bb[1], 0.f), A3[1], s + C3[1]);
                s = fmaf(fmaxf(a[2] + bb[2], 0.f), A3[2], s + C3[2]);
                s = fmaf(fmaxf(a[3] + bb[3], 0.f), A3[3], s + C3[3]);
                p[oo][rt2] += s;
            }
        }
    }
#pragma unroll
    for (int oo = 0; oo < 2; ++oo)
#pragma unroll
        for (int rt2 = 0; rt2 < 4; ++rt2) {
            float v = p[oo][rt2];
            v += __shfl_xor(v, 16);
            v += __shfl_xor(v, 32);
            p[oo][rt2] = v;
        }

    const int oo_s = l >> 5;
    const int bsel = (l >> 4) & 1;
    const int o_s = w * 2 + oo_s;
    const float b3v = pb3[o_s * NT + t];
    const float v0 = oo_s ? (bsel ? p[1][1] : p[1][0]) : (bsel ? p[0][1] : p[0][0]);
    const float v1 = oo_s ? (bsel ? p[1][3] : p[1][2]) : (bsel ? p[0][3] : p[0][2]);
    const int rg0 = bsel * 16 + (l & 15);
    const int ra = __shfl(rid_reg, rg0);
    const int rb = __shfl(rid_reg, rg0 + 32);
    if (ra >= 0) out[(size_t)ra * NO + o_s] = v0 + b3v;
    if (rb >= 0) out[(size_t)rb * NO + o_s] = v1 + b3v;
}

extern "C" void kernel_launch(void* const* d_in, const int* in_sizes, int n_in,
                              void* d_out, int out_size, void* d_ws, size_t ws_size,
                              hipStream_t stream) {
    const float* X   = (const float*)d_in[0];
    const int* trt   = (const int*)d_in[1];
    const float* W1  = (const float*)d_in[2];
    const float* b1  = (const float*)d_in[3];
    const float* g1  = (const float*)d_in[4];
    const float* be1 = (const float*)d_in[5];
    const float* m1  = (const float*)d_in[6];
    const float* v1  = (const float*)d_in[7];
    const float* W2  = (const float*)d_in[8];
    const float* b2  = (const float*)d_in[9];
    const float* g2  = (const float*)d_in[10];
    const float* be2 = (const float*)d_in[11];
    const float* m2  = (const float*)d_in[12];
    const float* v2  = (const float*)d_in[13];
    const float* W3  = (const float*)d_in[14];
    const float* b3  = (const float*)d_in[15];
    float* out = (float*)d_out;

    const int B = in_sizes[1];
    const int permCap = B + NT * BM;                 // padded-bucket capacity
    int* wsi  = (int*)d_ws;
    int* perm = wsi + 16;
    char* wsb = (char*)d_ws;
    size_t off = 64 + (size_t)permCap * 4;
    off = (off + 15) & ~(size_t)15;
    unsigned* W1T4 = (unsigned*)(wsb + off);
    unsigned* W2T4 = (unsigned*)(wsb + off + 1048576);

    const int nb = (B + 255) / 256;
    const int nbi = (permCap + 255) / 256;
    k_init<<<nbi, 256, 0, stream>>>(wsi, perm, permCap);
    k_hist<<<nb, 256, 0, stream>>>(trt, wsi, B);
    k_prefix<<<1, 1, 0, stream>>>(wsi);
    k_scatter<<<nb, 256, 0, stream>>>(trt, wsi, perm, B);
    k_prep<<<288, 256, 0, stream>>>(W1, W2, W1T4, W2T4);

    const int gx = (B + NT * BM) / BM;               // covers padded total
    k_main<<<gx, 256, 0, stream>>>(X, wsi, perm,
                                   (const unsigned short*)W1T4, (const unsigned short*)W2T4,
                                   b1, g1, be1, m1, v1, b2, g2, be2, m2, v2, W3, b3, out);
}